// Round 1
// baseline (958.531 us; speedup 1.0000x reference)
//
#include <hip/hip_runtime.h>
#include <math.h>

#define BATCH 512
#define ITERS 1000
#define PLEN 25      // iterations per phase
#define PHASES 40    // producer phase p covers k = 25p+1 .. 25p+25

typedef float f32x2 __attribute__((ext_vector_type(2)));
typedef float f32x4 __attribute__((ext_vector_type(4)));

// readlane requires a WAVE-UNIFORM lane index (compile-time constants below).
__device__ __forceinline__ float rdlane(float v, int l) {
  return __int_as_float(__builtin_amdgcn_readlane(__float_as_int(v), l));
}
__device__ __forceinline__ f32x2 fma2(f32x2 a, f32x2 b, f32x2 c) {
#if __has_builtin(__builtin_elementwise_fma)
  return __builtin_elementwise_fma(a, b, c);
#else
  f32x2 r; r.x = fmaf(a.x, b.x, c.x); r.y = fmaf(a.y, b.y, c.y); return r;
#endif
}

// Register-resident Gauss-Jordan on [A|I] (32x64); lane holds column `lane`.
#define GJ32_REG(g)                                            \
  _Pragma("unroll")                                            \
  for (int k = 0; k < 32; ++k) {                               \
    float inv = 1.0f / rdlane(g[k], k);                        \
    g[k] *= inv;                                               \
    _Pragma("unroll")                                          \
    for (int ii = 0; ii < 32; ++ii) {                          \
      if (ii == k) continue;                                   \
      float f = rdlane(g[ii], k);                              \
      g[ii] = fmaf(-f, g[k], g[ii]);                           \
    }                                                          \
  }

// Consumer: drain one 25-slot ring for one row -> Xs stores + primal GEMV.
#define CONSUME25(rx1, rx2, Xk, obk, blv)                      \
  _Pragma("unroll 1")                                          \
  for (int u = 0; u < PLEN; ++u) {                             \
    float x1v  = (rx1)[u * 64 + lane];                         \
    float x2mb = (rx2)[u * 64 + lane];                         \
    (Xk)[u * 128 + lane] = x1v;                                \
    (Xk)[u * 128 + 64 + lane] = x2mb + (blv);                  \
    const f32x4* tp = (const f32x4*)((rx2) + u * 64 + h * 32); \
    f32x2 pa = {0.f, 0.f}, pb = {0.f, 0.f};                    \
    _Pragma("unroll")                                          \
    for (int t = 0; t < 8; ++t) {                              \
      f32x4 tv = tp[t];                                        \
      pa = fma2(hv2[2*t],     tv.xy, pa);                      \
      pb = fma2(hv2[2*t + 1], tv.zw, pb);                      \
    }                                                          \
    float pr = (pa.x + pa.y) + (pb.x + pb.y);                  \
    pr += __shfl_xor(pr, 32);                                  \
    if (h == 0) (obk)[u * 32 + i] = pr;                        \
  }

// 2 batch rows per block. wave 0 = iterator for BOTH rows, interleaved as two
// independent dependency chains (fills readlane/FMA latency bubbles that left
// VALUBusy at 39% with a single chain). wave 1 = consumer for both rows.
// D, s, P^-1, Hinv are row-independent: setup cost per block is unchanged.
__global__ __launch_bounds__(128, 1)
void fused_kernel(const float* __restrict__ q,
                  const float* __restrict__ bmat,
                  const float* __restrict__ P,
                  const float* __restrict__ H,
                  float* __restrict__ Xs,
                  float* __restrict__ out2) {
  __shared__ __align__(16) float stage[2112];             // Hl 64x33 -> HT 32x66
  __shared__ __align__(16) float X1R[2][2][PLEN][64];     // ring: [buf][row][u][lane]
  __shared__ __align__(16) float X2R[2][2][PLEN][64];     // ring: x2 - b

  const int tid = threadIdx.x;
  const int wv = tid >> 6;          // 0 = iterator, 1 = consumer
  const int lane = tid & 63;
  const int r0 = blockIdx.x * 2;    // rows r0, r0+1
  const int i = lane & 31, h = lane >> 5;

  // ---- H row `lane` (both waves need it) ----
  float hreg[32];
  {
    const f32x4* hp = (const f32x4*)(H + lane * 32);
    #pragma unroll
    for (int j4 = 0; j4 < 8; ++j4) {
      f32x4 t = hp[j4];
      hreg[4*j4+0] = t.x; hreg[4*j4+1] = t.y; hreg[4*j4+2] = t.z; hreg[4*j4+3] = t.w;
    }
  }
  const float bla = bmat[r0 * 64 + lane];
  const float blb = bmat[r0 * 64 + 64 + lane];

  float dcol[64]; float s = 0.f, mua = 0.f, mub = 0.f;  // iterator state
  f32x2 hv2[16];                                        // consumer state
  float* Xpa = Xs + (size_t)r0 * (ITERS + 1) * 128;
  float* Xpb = Xpa + (size_t)(ITERS + 1) * 128;
  float* oba = out2 + (size_t)r0 * (ITERS + 1) * 32;
  float* obb = oba + (size_t)(ITERS + 1) * 32;

  // ---------- wave-1 Hinv transpose (block-wide barriers B1..B3) ----------
  if (wv == 1) {
    #pragma unroll
    for (int j = 0; j < 32; ++j) stage[lane * 33 + j] = hreg[j];
  }
  __syncthreads();                                // B1
  float gB[32];
  if (wv == 1) {
    float htc[64];                                // htc[m] = H[m][i]
    #pragma unroll
    for (int m = 0; m < 64; ++m) htc[m] = stage[m * 33 + i];
    #pragma unroll
    for (int r = 0; r < 32; ++r) {
      float a0 = 0.f, a1 = 0.f;
      #pragma unroll
      for (int m = 0; m < 64; m += 2) {
        a0 = fmaf(rdlane(hreg[r], m),     htc[m],     a0);
        a1 = fmaf(rdlane(hreg[r], m + 1), htc[m + 1], a1);
      }
      float hth = a0 + a1;                        // (H^T H)[r][i]
      gB[r] = (lane < 32) ? hth : (((lane - 32) == r) ? 1.0f : 0.0f);
    }
    GJ32_REG(gB)
  }
  __syncthreads();                                // B2
  if (wv == 1) {
    #pragma unroll
    for (int r = 0; r < 32; ++r) {                // Hinv[r][lane] -> staging
      float a0 = 0.f, a1 = 0.f;
      #pragma unroll
      for (int c = 0; c < 32; c += 2) {
        a0 = fmaf(rdlane(gB[r], 32 + c),     hreg[c],     a0);
        a1 = fmaf(rdlane(gB[r], 32 + c + 1), hreg[c + 1], a1);
      }
      stage[r * 66 + lane] = a0 + a1;
    }
  }
  __syncthreads();                                // B3
  if (wv == 1) {
    #pragma unroll
    for (int t = 0; t < 16; ++t)                  // lane (h,i): Hinv[i][32h+2t..+1]
      hv2[t] = *(const f32x2*)&stage[i * 66 + 32 * h + 2 * t];
  }

  if (wv == 0) {
    // ---------- setup (registers only): P^-1, P^-1 H^T, D, lambda_max ----------
    float pht[32], acca, accb;
    {
      float g[32];
      #pragma unroll
      for (int r = 0; r < 32; ++r) {
        float pv = P[r * 32 + i];
        g[r] = (lane < 32) ? pv : (((lane - 32) == r) ? 1.0f : 0.0f);
      }
      GJ32_REG(g)
      #pragma unroll
      for (int r = 0; r < 32; ++r) {      // (P^-1 H^T)[r][lane]
        float a0 = 0.f, a1 = 0.f;
        #pragma unroll
        for (int j = 0; j < 32; j += 2) {
          a0 = fmaf(rdlane(g[r], 32 + j),     hreg[j],     a0);
          a1 = fmaf(rdlane(g[r], 32 + j + 1), hreg[j + 1], a1);
        }
        pht[r] = a0 + a1;
      }
    }
    {
      const float* qa = q + r0 * 32;      // wave-uniform -> s_loads
      const float* qb = qa + 32;
      float a0 = 0.f, a1 = 0.f, b0 = 0.f, b1 = 0.f;
      #pragma unroll
      for (int r = 0; r < 32; r += 2) {
        a0 = fmaf(qa[r],     pht[r],     a0);
        a1 = fmaf(qa[r + 1], pht[r + 1], a1);
        b0 = fmaf(qb[r],     pht[r],     b0);
        b1 = fmaf(qb[r + 1], pht[r + 1], b1);
      }
      acca = a0 + a1;                     // (H P^-1 q_r0)[lane]
      accb = b0 + b1;                     // (H P^-1 q_r1)[lane]
    }
    #pragma unroll
    for (int r = 0; r < 64; ++r) {        // D[r][lane] (symmetric)
      float a0 = 0.f, a1 = 0.f;
      #pragma unroll
      for (int j = 0; j < 32; j += 2) {
        a0 = fmaf(rdlane(hreg[j],     r), pht[j],     a0);
        a1 = fmaf(rdlane(hreg[j + 1], r), pht[j + 1], a1);
      }
      dcol[r] = a0 + a1;
    }
    {
      float ecol[64];                     // E = D^2 (squares convergence rate)
      #pragma unroll
      for (int r = 0; r < 64; ++r) {
        float a0 = 0.f, a1 = 0.f;
        #pragma unroll
        for (int c = 0; c < 64; c += 2) {
          a0 = fmaf(rdlane(dcol[r], c),     dcol[c],     a0);
          a1 = fmaf(rdlane(dcol[r], c + 1), dcol[c + 1], a1);
        }
        ecol[r] = a0 + a1;
      }
      float v = 1.0f + 0.017f * (float)lane;
      #pragma unroll 1
      for (int t = 0; t < 112; ++t) {
        float a0 = 0.f, a1 = 0.f, a2 = 0.f, a3 = 0.f;
        #pragma unroll
        for (int c = 0; c < 64; c += 4) {
          a0 = fmaf(ecol[c+0], rdlane(v, c+0), a0);
          a1 = fmaf(ecol[c+1], rdlane(v, c+1), a1);
          a2 = fmaf(ecol[c+2], rdlane(v, c+2), a2);
          a3 = fmaf(ecol[c+3], rdlane(v, c+3), a3);
        }
        v = (a0 + a1) + (a2 + a3);
        if ((t & 7) == 7) {
          float n2 = v * v;
          #pragma unroll
          for (int m = 1; m < 64; m <<= 1) n2 += __shfl_xor(n2, m);
          v *= 1.0f / sqrtf(n2);
        }
      }
      float a0 = 0.f, a1 = 0.f, a2 = 0.f, a3 = 0.f;  // Rayleigh with D
      #pragma unroll
      for (int c = 0; c < 64; c += 4) {
        a0 = fmaf(dcol[c+0], rdlane(v, c+0), a0);
        a1 = fmaf(dcol[c+1], rdlane(v, c+1), a1);
        a2 = fmaf(dcol[c+2], rdlane(v, c+2), a2);
        a3 = fmaf(dcol[c+3], rdlane(v, c+3), a3);
      }
      float w = (a0 + a1) + (a2 + a3);
      float num = w * v, den = v * v;
      #pragma unroll
      for (int m = 1; m < 64; m <<= 1) {
        num += __shfl_xor(num, m);
        den += __shfl_xor(den, m);
      }
      s = den / num;                      // s = 1 / lambda_max(D)
    }
    mua = s * (acca - bla);
    mub = s * (accb - blb);
    #pragma unroll
    for (int r = 0; r < 64; ++r) dcol[r] *= s;   // row `lane` of s*D
  }

  // ---------- main loop: 40 phases x 25 iterations, 2 rows interleaved ----------
  float x1a = 0.f, x2a = 0.f, x1b = 0.f, x2b = 0.f;
  #pragma unroll 1
  for (int p = 0; p < PHASES; ++p) {
    if (wv == 0) {
      float* rx1a = &X1R[p & 1][0][0][0];
      float* rx2a = &X2R[p & 1][0][0][0];
      float* rx1b = &X1R[p & 1][1][0][0];
      float* rx2b = &X2R[p & 1][1][0][0];
      #pragma unroll 1
      for (int u = 0; u < PLEN; ++u) {
        float ta = fmaf(s, x2a, mua), tb = fmaf(s, x2b, mub);
        float a0 = 0.f, a1 = 0.f, a2 = 0.f, a3 = 0.f;
        float c0 = 0.f, c1 = 0.f, c2 = 0.f, c3 = 0.f;
        // Two independent chains (rows a,b): 16 readlanes batched ahead of
        // their FMAs; A/B FMAs alternate so each chain's hazards are buried
        // under the other chain's issue slots.
        #pragma unroll
        for (int j8 = 0; j8 < 64; j8 += 8) {
          float pa0 = rdlane(x1a, j8+0), pa1 = rdlane(x1a, j8+1);
          float pa2 = rdlane(x1a, j8+2), pa3 = rdlane(x1a, j8+3);
          float pa4 = rdlane(x1a, j8+4), pa5 = rdlane(x1a, j8+5);
          float pa6 = rdlane(x1a, j8+6), pa7 = rdlane(x1a, j8+7);
          float pb0 = rdlane(x1b, j8+0), pb1 = rdlane(x1b, j8+1);
          float pb2 = rdlane(x1b, j8+2), pb3 = rdlane(x1b, j8+3);
          float pb4 = rdlane(x1b, j8+4), pb5 = rdlane(x1b, j8+5);
          float pb6 = rdlane(x1b, j8+6), pb7 = rdlane(x1b, j8+7);
          a0 = fmaf(dcol[j8+0], pa0, a0);
          c0 = fmaf(dcol[j8+0], pb0, c0);
          a1 = fmaf(dcol[j8+1], pa1, a1);
          c1 = fmaf(dcol[j8+1], pb1, c1);
          a2 = fmaf(dcol[j8+2], pa2, a2);
          c2 = fmaf(dcol[j8+2], pb2, c2);
          a3 = fmaf(dcol[j8+3], pa3, a3);
          c3 = fmaf(dcol[j8+3], pb3, c3);
          a0 = fmaf(dcol[j8+4], pa4, a0);
          c0 = fmaf(dcol[j8+4], pb4, c0);
          a1 = fmaf(dcol[j8+5], pa5, a1);
          c1 = fmaf(dcol[j8+5], pb5, c1);
          a2 = fmaf(dcol[j8+6], pa6, a2);
          c2 = fmaf(dcol[j8+6], pb6, c2);
          a3 = fmaf(dcol[j8+7], pa7, a3);
          c3 = fmaf(dcol[j8+7], pb7, c3);
        }
        float x1na = ((a0 + a1) + (a2 + a3)) + ta;
        float x1nb = ((c0 + c1) + (c2 + c3)) + tb;
        float x2na = fmaxf(fmaf(-2.0f, x1na, x1a + x2a), 0.f);
        float x2nb = fmaxf(fmaf(-2.0f, x1nb, x1b + x2b), 0.f);
        rx1a[u * 64 + lane] = x1na;
        rx2a[u * 64 + lane] = x2na - bla;
        rx1b[u * 64 + lane] = x1nb;
        rx2b[u * 64 + lane] = x2nb - blb;
        x1a = x1na; x2a = x2na; x1b = x1nb; x2b = x2nb;
      }
    } else {
      if (p == 0) {
        // k = 0: X0 = 0 stores + primal_0 = Hinv @ (-b), both rows
        Xpa[lane] = 0.f; Xpa[64 + lane] = 0.f;
        Xpb[lane] = 0.f; Xpb[64 + lane] = 0.f;
        {
          f32x2 pa = {0.f, 0.f}, pb = {0.f, 0.f};
          #pragma unroll
          for (int t = 0; t < 8; ++t) {
            f32x2 ta, tb;
            ta.x = -__shfl(bla, 32*h + 4*t + 0, 64);
            ta.y = -__shfl(bla, 32*h + 4*t + 1, 64);
            tb.x = -__shfl(bla, 32*h + 4*t + 2, 64);
            tb.y = -__shfl(bla, 32*h + 4*t + 3, 64);
            pa = fma2(hv2[2*t],     ta, pa);
            pb = fma2(hv2[2*t + 1], tb, pb);
          }
          float pr = (pa.x + pa.y) + (pb.x + pb.y);
          pr += __shfl_xor(pr, 32);
          if (h == 0) oba[i] = pr;
        }
        {
          f32x2 pa = {0.f, 0.f}, pb = {0.f, 0.f};
          #pragma unroll
          for (int t = 0; t < 8; ++t) {
            f32x2 ta, tb;
            ta.x = -__shfl(blb, 32*h + 4*t + 0, 64);
            ta.y = -__shfl(blb, 32*h + 4*t + 1, 64);
            tb.x = -__shfl(blb, 32*h + 4*t + 2, 64);
            tb.y = -__shfl(blb, 32*h + 4*t + 3, 64);
            pa = fma2(hv2[2*t],     ta, pa);
            pb = fma2(hv2[2*t + 1], tb, pb);
          }
          float pr = (pa.x + pa.y) + (pb.x + pb.y);
          pr += __shfl_xor(pr, 32);
          if (h == 0) obb[i] = pr;
        }
      } else {
        const int k0 = PLEN * (p - 1) + 1;
        CONSUME25(&X1R[(p - 1) & 1][0][0][0], &X2R[(p - 1) & 1][0][0][0],
                  Xpa + (size_t)k0 * 128, oba + (size_t)k0 * 32, bla)
        CONSUME25(&X1R[(p - 1) & 1][1][0][0], &X2R[(p - 1) & 1][1][0][0],
                  Xpb + (size_t)k0 * 128, obb + (size_t)k0 * 32, blb)
      }
    }
    __syncthreads();                      // both waves, every phase
  }

  if (wv == 1) {
    // tail: phase 39 data (buffer 1), k = 976..1000, both rows
    const int k0 = PLEN * (PHASES - 1) + 1;
    CONSUME25(&X1R[1][0][0][0], &X2R[1][0][0][0],
              Xpa + (size_t)k0 * 128, oba + (size_t)k0 * 32, bla)
    CONSUME25(&X1R[1][1][0][0], &X2R[1][1][0][0],
              Xpb + (size_t)k0 * 128, obb + (size_t)k0 * 32, blb)
  }
}

extern "C" void kernel_launch(void* const* d_in, const int* in_sizes, int n_in,
                              void* d_out, int out_size, void* d_ws, size_t ws_size,
                              hipStream_t stream) {
  (void)in_sizes; (void)n_in; (void)out_size; (void)d_ws; (void)ws_size;
  const float* q = (const float*)d_in[0];
  const float* b = (const float*)d_in[1];
  const float* P = (const float*)d_in[2];
  const float* H = (const float*)d_in[3];
  float* Xs = (float*)d_out;
  float* out2 = Xs + (size_t)BATCH * (ITERS + 1) * 128;

  fused_kernel<<<BATCH / 2, 128, 0, stream>>>(q, b, P, H, Xs, out2);
}

// Round 2
// 577.354 us; speedup vs baseline: 1.6602x; 1.6602x over previous
//
#include <hip/hip_runtime.h>
#include <math.h>

#define BATCH 512
#define ITERS 1000
#define PLEN 25      // iterations per phase
#define PHASES 40    // producer phase p covers k = 25p+1 .. 25p+25

typedef float f32x2 __attribute__((ext_vector_type(2)));
typedef float f32x4 __attribute__((ext_vector_type(4)));

// readlane requires a WAVE-UNIFORM lane index (compile-time constants below).
__device__ __forceinline__ float rdlane(float v, int l) {
  return __int_as_float(__builtin_amdgcn_readlane(__float_as_int(v), l));
}
__device__ __forceinline__ f32x2 fma2(f32x2 a, f32x2 b, f32x2 c) {
#if __has_builtin(__builtin_elementwise_fma)
  return __builtin_elementwise_fma(a, b, c);
#else
  f32x2 r; r.x = fmaf(a.x, b.x, c.x); r.y = fmaf(a.y, b.y, c.y); return r;
#endif
}

// sD row `lane` stored as 32 packed f32x2 (for v_pk_fma_f32). Element access
// for the setup code (all indices compile-time constants in unrolled loops):
#define DC(c) (((c) & 1) ? dcol2[(c) >> 1].y : dcol2[(c) >> 1].x)

// Register-resident Gauss-Jordan on [A|I] (32x64); lane holds column `lane`.
#define GJ32_REG(g)                                            \
  _Pragma("unroll")                                            \
  for (int k = 0; k < 32; ++k) {                               \
    float inv = 1.0f / rdlane(g[k], k);                        \
    g[k] *= inv;                                               \
    _Pragma("unroll")                                          \
    for (int ii = 0; ii < 32; ++ii) {                          \
      if (ii == k) continue;                                   \
      float f = rdlane(g[ii], k);                              \
      g[ii] = fmaf(-f, g[k], g[ii]);                           \
    }                                                          \
  }

// wave 0 = iterator, wave 1 = consumer (Xs stores + primal GEMV + store).
// v3 change vs v0: the iterator's x1 broadcast no longer uses 64 v_readlane
// per iteration (measured fixed ~6.2 cyc/instr solo-wave cadence made the
// loop instruction-count-bound). Instead: x1 is re-read from the LDS ring it
// already writes, as 16 uniform-address ds_read_b128 (broadcast, conflict-
// free), and the matvec uses 32 packed f32x2 FMAs. ~60 instrs/iter vs ~140.
__global__ __launch_bounds__(128, 1)
void fused_kernel(const float* __restrict__ q,
                  const float* __restrict__ bmat,
                  const float* __restrict__ P,
                  const float* __restrict__ H,
                  float* __restrict__ Xs,
                  float* __restrict__ out2) {
  __shared__ __align__(16) float stage[2112];        // wave 1: Hl 64x33 -> HT 32x66
  __shared__ __align__(16) float X1R[2][PLEN][64];   // ring: x1
  __shared__ __align__(16) float X2R[2][PLEN][64];   // ring: x2 - b

  const int tid = threadIdx.x;
  const int wv = tid >> 6;          // 0 = iterator, 1 = consumer
  const int lane = tid & 63;
  const int row = blockIdx.x;
  const int i = lane & 31, h = lane >> 5;

  // ---- H row `lane` (both waves need it) ----
  float hreg[32];
  {
    const f32x4* hp = (const f32x4*)(H + lane * 32);
    #pragma unroll
    for (int j4 = 0; j4 < 8; ++j4) {
      f32x4 t = hp[j4];
      hreg[4*j4+0] = t.x; hreg[4*j4+1] = t.y; hreg[4*j4+2] = t.z; hreg[4*j4+3] = t.w;
    }
  }
  const float bl = bmat[row * 64 + lane];

  f32x2 dcol2[32]; float s = 0.f, mu = 0.f;       // iterator state
  f32x4 xb[16];                                   // broadcast x1 (iterator)
  float x1 = 0.f, x2 = 0.f;
  f32x2 hv2[16];                                  // consumer state
  float* Xp = Xs + (size_t)row * (ITERS + 1) * 128;
  float* ob = out2 + (size_t)row * (ITERS + 1) * 32;

  // ---------- wave-1 Hinv transpose (block-wide barriers B1..B3) ----------
  if (wv == 1) {
    #pragma unroll
    for (int j = 0; j < 32; ++j) stage[lane * 33 + j] = hreg[j];
  }
  __syncthreads();                                // B1
  float gB[32];
  if (wv == 1) {
    float htc[64];                                // htc[m] = H[m][i]
    #pragma unroll
    for (int m = 0; m < 64; ++m) htc[m] = stage[m * 33 + i];
    #pragma unroll
    for (int r = 0; r < 32; ++r) {
      float a0 = 0.f, a1 = 0.f;
      #pragma unroll
      for (int m = 0; m < 64; m += 2) {
        a0 = fmaf(rdlane(hreg[r], m),     htc[m],     a0);
        a1 = fmaf(rdlane(hreg[r], m + 1), htc[m + 1], a1);
      }
      float hth = a0 + a1;                        // (H^T H)[r][i]
      gB[r] = (lane < 32) ? hth : (((lane - 32) == r) ? 1.0f : 0.0f);
    }
    GJ32_REG(gB)
  }
  __syncthreads();                                // B2
  if (wv == 1) {
    #pragma unroll
    for (int r = 0; r < 32; ++r) {                // Hinv[r][lane] -> staging
      float a0 = 0.f, a1 = 0.f;
      #pragma unroll
      for (int c = 0; c < 32; c += 2) {
        a0 = fmaf(rdlane(gB[r], 32 + c),     hreg[c],     a0);
        a1 = fmaf(rdlane(gB[r], 32 + c + 1), hreg[c + 1], a1);
      }
      stage[r * 66 + lane] = a0 + a1;
    }
  }
  __syncthreads();                                // B3
  if (wv == 1) {
    #pragma unroll
    for (int t = 0; t < 16; ++t)                  // lane (h,i): Hinv[i][32h+2t..+1]
      hv2[t] = *(const f32x2*)&stage[i * 66 + 32 * h + 2 * t];
  }

  if (wv == 0) {
    // ---------- setup (registers only): P^-1, P^-1 H^T, D, lambda_max ----------
    float pht[32], acc;
    {
      float g[32];
      #pragma unroll
      for (int r = 0; r < 32; ++r) {
        float pv = P[r * 32 + i];
        g[r] = (lane < 32) ? pv : (((lane - 32) == r) ? 1.0f : 0.0f);
      }
      GJ32_REG(g)
      #pragma unroll
      for (int r = 0; r < 32; ++r) {      // (P^-1 H^T)[r][lane]
        float a0 = 0.f, a1 = 0.f;
        #pragma unroll
        for (int j = 0; j < 32; j += 2) {
          a0 = fmaf(rdlane(g[r], 32 + j),     hreg[j],     a0);
          a1 = fmaf(rdlane(g[r], 32 + j + 1), hreg[j + 1], a1);
        }
        pht[r] = a0 + a1;
      }
    }
    {
      const float* qp = q + row * 32;     // wave-uniform -> s_loads
      float a0 = 0.f, a1 = 0.f;
      #pragma unroll
      for (int r = 0; r < 32; r += 2) {
        a0 = fmaf(qp[r],     pht[r],     a0);
        a1 = fmaf(qp[r + 1], pht[r + 1], a1);
      }
      acc = a0 + a1;                      // (H P^-1 q)[lane]
    }
    #pragma unroll
    for (int r = 0; r < 64; ++r) {        // D[r][lane] (symmetric)
      float a0 = 0.f, a1 = 0.f;
      #pragma unroll
      for (int j = 0; j < 32; j += 2) {
        a0 = fmaf(rdlane(hreg[j],     r), pht[j],     a0);
        a1 = fmaf(rdlane(hreg[j + 1], r), pht[j + 1], a1);
      }
      float val = a0 + a1;
      if (r & 1) dcol2[r >> 1].y = val; else dcol2[r >> 1].x = val;
    }
    {
      float ecol[64];                     // E = D^2 (squares convergence rate)
      #pragma unroll
      for (int r = 0; r < 64; ++r) {
        float a0 = 0.f, a1 = 0.f;
        #pragma unroll
        for (int c = 0; c < 64; c += 2) {
          a0 = fmaf(rdlane(DC(r), c),     DC(c),     a0);
          a1 = fmaf(rdlane(DC(r), c + 1), DC(c + 1), a1);
        }
        ecol[r] = a0 + a1;
      }
      float v = 1.0f + 0.017f * (float)lane;
      #pragma unroll 1
      for (int t = 0; t < 112; ++t) {
        float a0 = 0.f, a1 = 0.f, a2 = 0.f, a3 = 0.f;
        #pragma unroll
        for (int c = 0; c < 64; c += 4) {
          a0 = fmaf(ecol[c+0], rdlane(v, c+0), a0);
          a1 = fmaf(ecol[c+1], rdlane(v, c+1), a1);
          a2 = fmaf(ecol[c+2], rdlane(v, c+2), a2);
          a3 = fmaf(ecol[c+3], rdlane(v, c+3), a3);
        }
        v = (a0 + a1) + (a2 + a3);
        if ((t & 7) == 7) {
          float n2 = v * v;
          #pragma unroll
          for (int m = 1; m < 64; m <<= 1) n2 += __shfl_xor(n2, m);
          v *= 1.0f / sqrtf(n2);
        }
      }
      float a0 = 0.f, a1 = 0.f, a2 = 0.f, a3 = 0.f;  // Rayleigh with D
      #pragma unroll
      for (int c = 0; c < 64; c += 4) {
        a0 = fmaf(DC(c+0), rdlane(v, c+0), a0);
        a1 = fmaf(DC(c+1), rdlane(v, c+1), a1);
        a2 = fmaf(DC(c+2), rdlane(v, c+2), a2);
        a3 = fmaf(DC(c+3), rdlane(v, c+3), a3);
      }
      float w = (a0 + a1) + (a2 + a3);
      float num = w * v, den = v * v;
      #pragma unroll
      for (int m = 1; m < 64; m <<= 1) {
        num += __shfl_xor(num, m);
        den += __shfl_xor(den, m);
      }
      s = den / num;                      // s = 1 / lambda_max(D)
    }
    mu = s * (acc - bl);
    #pragma unroll
    for (int t = 0; t < 32; ++t) dcol2[t] *= s;  // row `lane` of s*D, packed

    // ---- prologue: k = 1 directly (X0 = 0 -> x1 = mu, x2 = relu(-2 mu)) ----
    // Write ring row 0 of buffer 0, then issue the broadcast reads that
    // iteration u=1 will consume (same-wave DS ops are in-order: RAW safe).
    x1 = mu;
    x2 = fmaxf(-2.0f * mu, 0.f);
    X1R[0][0][lane] = x1;
    X2R[0][0][lane] = x2 - bl;
    {
      const f32x4* bp = (const f32x4*)&X1R[0][0][0];  // uniform addr: broadcast
      #pragma unroll
      for (int t = 0; t < 16; ++t) xb[t] = bp[t];
    }
  }

  // ---------- main loop: 40 phases x 25 iterations ----------
  #pragma unroll 1
  for (int p = 0; p < PHASES; ++p) {
    if (wv == 0) {
      float* rx1 = &X1R[p & 1][0][0];
      float* rx2 = &X2R[p & 1][0][0];
      #pragma unroll 1
      for (int u = (p == 0) ? 1 : 0; u < PLEN; ++u) {
        float ta = fmaf(s, x2, mu);
        f32x2 A0 = {0.f, 0.f}, A1 = {0.f, 0.f};
        f32x2 A2 = {0.f, 0.f}, A3 = {0.f, 0.f};
        // 32 packed FMAs: sD (packed pairs) * broadcast x1 (from LDS ring)
        #pragma unroll
        for (int t = 0; t < 16; t += 2) {
          A0 = fma2(dcol2[2*t + 0], xb[t].xy,     A0);
          A1 = fma2(dcol2[2*t + 1], xb[t].zw,     A1);
          A2 = fma2(dcol2[2*t + 2], xb[t + 1].xy, A2);
          A3 = fma2(dcol2[2*t + 3], xb[t + 1].zw, A3);
        }
        f32x2 R = (A0 + A1) + (A2 + A3);
        float x1n = (R.x + R.y) + ta;
        rx1[u * 64 + lane] = x1n;
        // issue next iteration's broadcast reads NOW (in-order DS pipe sees
        // the ring write above first); x2 tail below hides part of the latency
        {
          const f32x4* bp = (const f32x4*)(rx1 + u * 64);
          #pragma unroll
          for (int t = 0; t < 16; ++t) xb[t] = bp[t];
        }
        float x2n = fmaxf(fmaf(-2.0f, x1n, x1 + x2), 0.f);
        rx2[u * 64 + lane] = x2n - bl;
        x1 = x1n; x2 = x2n;
      }
    } else {
      if (p == 0) {
        // k = 0: X0 = 0 stores + primal_0 = Hinv @ (-b)
        Xp[lane] = 0.f;
        Xp[64 + lane] = 0.f;
        f32x2 pa = {0.f, 0.f}, pb = {0.f, 0.f};
        #pragma unroll
        for (int t = 0; t < 8; ++t) {
          f32x2 ta, tb;
          ta.x = -__shfl(bl, 32*h + 4*t + 0, 64);
          ta.y = -__shfl(bl, 32*h + 4*t + 1, 64);
          tb.x = -__shfl(bl, 32*h + 4*t + 2, 64);
          tb.y = -__shfl(bl, 32*h + 4*t + 3, 64);
          pa = fma2(hv2[2*t],     ta, pa);
          pb = fma2(hv2[2*t + 1], tb, pb);
        }
        float pr = (pa.x + pa.y) + (pb.x + pb.y);
        pr += __shfl_xor(pr, 32);
        if (h == 0) ob[i] = pr;
      } else {
        const float* rx1 = &X1R[(p - 1) & 1][0][0];
        const float* rx2 = &X2R[(p - 1) & 1][0][0];
        const int k0 = PLEN * (p - 1) + 1;
        float* Xk = Xp + (size_t)k0 * 128;
        float* obk = ob + (size_t)k0 * 32;
        #pragma unroll 1
        for (int u = 0; u < PLEN; ++u) {
          float x1v = rx1[u * 64 + lane];
          float x2mb = rx2[u * 64 + lane];
          Xk[u * 128 + lane] = x1v;
          Xk[u * 128 + 64 + lane] = x2mb + bl;
          const f32x4* tp = (const f32x4*)(rx2 + u * 64 + h * 32);
          f32x2 pa = {0.f, 0.f}, pb = {0.f, 0.f};
          #pragma unroll
          for (int t = 0; t < 8; ++t) {
            f32x4 tv = tp[t];
            pa = fma2(hv2[2*t],     tv.xy, pa);
            pb = fma2(hv2[2*t + 1], tv.zw, pb);
          }
          float pr = (pa.x + pa.y) + (pb.x + pb.y);
          pr += __shfl_xor(pr, 32);
          if (h == 0) obk[u * 32 + i] = pr;
        }
      }
    }
    __syncthreads();                      // both waves, every phase
  }

  if (wv == 1) {
    // tail: phase 39 data (buffer 1), k = 976..1000
    const float* rx1 = &X1R[1][0][0];
    const float* rx2 = &X2R[1][0][0];
    const int k0 = PLEN * (PHASES - 1) + 1;
    float* Xk = Xp + (size_t)k0 * 128;
    float* obk = ob + (size_t)k0 * 32;
    #pragma unroll 1
    for (int u = 0; u < PLEN; ++u) {
      float x1v = rx1[u * 64 + lane];
      float x2mb = rx2[u * 64 + lane];
      Xk[u * 128 + lane] = x1v;
      Xk[u * 128 + 64 + lane] = x2mb + bl;
      const f32x4* tp = (const f32x4*)(rx2 + u * 64 + h * 32);
      f32x2 pa = {0.f, 0.f}, pb = {0.f, 0.f};
      #pragma unroll
      for (int t = 0; t < 8; ++t) {
        f32x4 tv = tp[t];
        pa = fma2(hv2[2*t],     tv.xy, pa);
        pb = fma2(hv2[2*t + 1], tv.zw, pb);
      }
      float pr = (pa.x + pa.y) + (pb.x + pb.y);
      pr += __shfl_xor(pr, 32);
      if (h == 0) obk[u * 32 + i] = pr;
    }
  }
}

extern "C" void kernel_launch(void* const* d_in, const int* in_sizes, int n_in,
                              void* d_out, int out_size, void* d_ws, size_t ws_size,
                              hipStream_t stream) {
  (void)in_sizes; (void)n_in; (void)out_size; (void)d_ws; (void)ws_size;
  const float* q = (const float*)d_in[0];
  const float* b = (const float*)d_in[1];
  const float* P = (const float*)d_in[2];
  const float* H = (const float*)d_in[3];
  float* Xs = (float*)d_out;
  float* out2 = Xs + (size_t)BATCH * (ITERS + 1) * 128;

  fused_kernel<<<BATCH, 128, 0, stream>>>(q, b, P, H, Xs, out2);
}